// Round 4
// baseline (781.943 us; speedup 1.0000x reference)
//
#include <hip/hip_runtime.h>

// ---------------------------------------------------------------------------
// GCN forward: 3x (GEMM 50000x128x128 + CSR agg) + agg+pool (W3 commuted
// past the mean-pool) + fused final linear chain + softmax. All fp32.
// ---------------------------------------------------------------------------

__device__ __forceinline__ int idx_at(const void* p, long long i, int is64) {
  return is64 ? (int)((const long long*)p)[i] : ((const int*)p)[i];
}

__global__ void k_detect(const int* __restrict__ edge, int* __restrict__ flag) {
  if (threadIdx.x == 0 && blockIdx.x == 0) {
    int all0 = 1;
    for (int i = 1; i < 128; i += 2)
      if (edge[i] != 0) { all0 = 0; break; }
    *flag = all0;
  }
}

__global__ void k_count(const void* __restrict__ edge, int E,
                        int* __restrict__ cnt, const int* __restrict__ flag) {
  int e = blockIdx.x * 256 + threadIdx.x;
  int is64 = *flag;
  if (e < E) {
    int c = idx_at(edge, (long long)E + e, is64);  // col = target
    atomicAdd(&cnt[c], 1);
  }
}

__global__ void k_dinv(const int* __restrict__ cnt, int n, float* __restrict__ dinv) {
  int i = blockIdx.x * 256 + threadIdx.x;
  if (i < n) dinv[i] = rsqrtf((float)(cnt[i] + 1));  // +1 self loop
}

// --- 3-kernel exclusive scan over cnt[n] -> offs[n] -------------------------
__global__ void k_scan1(const int* __restrict__ cnt, int* __restrict__ offs,
                        int* __restrict__ bsum, int n) {
  __shared__ int lds[256];
  int i = blockIdx.x * 256 + threadIdx.x;
  int v = (i < n) ? cnt[i] : 0;
  lds[threadIdx.x] = v;
  __syncthreads();
  for (int off = 1; off < 256; off <<= 1) {
    int t = (threadIdx.x >= off) ? lds[threadIdx.x - off] : 0;
    __syncthreads();
    lds[threadIdx.x] += t;
    __syncthreads();
  }
  if (i < n) offs[i] = lds[threadIdx.x] - v;
  if (threadIdx.x == 255) bsum[blockIdx.x] = lds[255];
}

__global__ void k_scan2(int* __restrict__ bsum, int nb) {
  __shared__ int lds[256];
  int v = (threadIdx.x < nb) ? bsum[threadIdx.x] : 0;
  lds[threadIdx.x] = v;
  __syncthreads();
  for (int off = 1; off < 256; off <<= 1) {
    int t = (threadIdx.x >= off) ? lds[threadIdx.x - off] : 0;
    __syncthreads();
    lds[threadIdx.x] += t;
    __syncthreads();
  }
  if (threadIdx.x < nb) bsum[threadIdx.x] = lds[threadIdx.x] - v;
}

__global__ void k_scan3(int* __restrict__ offs, int* __restrict__ cursor,
                        const int* __restrict__ bsum, int n, int E) {
  int i = blockIdx.x * 256 + threadIdx.x;
  if (i < n) {
    int o = offs[i] + bsum[blockIdx.x];
    offs[i] = o;
    cursor[i] = o;
  }
  if (i == 0) offs[n] = E;
}

// csr_pair[p] = {source_row, bitcast(norm)}
__global__ void k_fill(const void* __restrict__ edge, int E,
                       const float* __restrict__ dinv, int* __restrict__ cursor,
                       int2* __restrict__ csr_pair, const int* __restrict__ flag) {
  int e = blockIdx.x * 256 + threadIdx.x;
  int is64 = *flag;
  if (e < E) {
    int r = idx_at(edge, e, is64);
    int c = idx_at(edge, (long long)E + e, is64);
    int p = atomicAdd(&cursor[c], 1);
    float nm = dinv[r] * dinv[c];
    csr_pair[p] = int2{r, __float_as_int(nm)};
  }
}

// --- GEMM: C[n x 128] = A[n x 128] @ W[128 x 128] ---------------------------
// W staged in LDS once per block (64 KB -> 2 blocks/CU); A streamed from
// global (read-once, broadcast per half-wave); NO per-tile barriers.
#define GR 64
__global__ __launch_bounds__(256) void k_gemm(const float* __restrict__ A,
                                              const float* __restrict__ W,
                                              float* __restrict__ C,
                                              int n, int ntiles) {
  __shared__ float4 Wl[128 * 32];  // 64 KB
  const float4* W4 = (const float4*)W;
  const float4* A4 = (const float4*)A;
  float4* C4 = (float4*)C;
  int t = threadIdx.x;
#pragma unroll
  for (int j = 0; j < 16; j++) Wl[t + 256 * j] = W4[t + 256 * j];
  __syncthreads();
  int tr = t >> 5;   // 0..7 (row group of 8)
  int tc = t & 31;   // 0..31 (float4 col)
  for (int tile = blockIdx.x; tile < ntiles; tile += gridDim.x) {
    int base = tile * GR;
    int r0 = base + tr * 8;
    const float4* ap[8];
#pragma unroll
    for (int ii = 0; ii < 8; ii++) {
      int rr = r0 + ii;
      if (rr > n - 1) rr = n - 1;  // clamp: safe load, store guarded below
      ap[ii] = A4 + (size_t)rr * 32;
    }
    float4 acc[8];
#pragma unroll
    for (int ii = 0; ii < 8; ii++) acc[ii] = float4{0, 0, 0, 0};
#pragma unroll 2
    for (int k4 = 0; k4 < 32; k4++) {
      float4 w0 = Wl[(4 * k4 + 0) * 32 + tc];
      float4 w1 = Wl[(4 * k4 + 1) * 32 + tc];
      float4 w2 = Wl[(4 * k4 + 2) * 32 + tc];
      float4 w3 = Wl[(4 * k4 + 3) * 32 + tc];
#pragma unroll
      for (int ii = 0; ii < 8; ii++) {
        float4 a = ap[ii][k4];
        acc[ii].x += a.x * w0.x + a.y * w1.x + a.z * w2.x + a.w * w3.x;
        acc[ii].y += a.x * w0.y + a.y * w1.y + a.z * w2.y + a.w * w3.y;
        acc[ii].z += a.x * w0.z + a.y * w1.z + a.z * w2.z + a.w * w3.z;
        acc[ii].w += a.x * w0.w + a.y * w1.w + a.z * w2.w + a.w * w3.w;
      }
    }
#pragma unroll
    for (int ii = 0; ii < 8; ii++) {
      int gr = r0 + ii;
      if (gr < n) C4[(size_t)gr * 32 + tc] = acc[ii];
    }
  }
}

// --- Gather core: one wave per node, 2 floats/lane, 8-deep pipeline ---------
__device__ __forceinline__ float2 gather_node(const float2* __restrict__ h2,
                                              const int* __restrict__ offs,
                                              const int2* __restrict__ csr_pair,
                                              const float* __restrict__ dinv,
                                              int node, int lane) {
  int s = offs[node], e = offs[node + 1];
  float dn = dinv[node];
  float2 self = h2[(size_t)node * 64 + lane];
  float ax = self.x * dn * dn;
  float ay = self.y * dn * dn;
  int i = s;
  if ((i & 1) && i < e) {  // align to int4 pairs
    int2 p = csr_pair[i];
    float2 v = h2[(size_t)p.x * 64 + lane];
    float f = __int_as_float(p.y);
    ax += v.x * f; ay += v.y * f;
    i++;
  }
  const int4* cp4 = (const int4*)csr_pair;
  for (; i + 8 <= e; i += 8) {
    int4 q0 = cp4[(i >> 1) + 0];
    int4 q1 = cp4[(i >> 1) + 1];
    int4 q2 = cp4[(i >> 1) + 2];
    int4 q3 = cp4[(i >> 1) + 3];
    float2 v0 = h2[(size_t)q0.x * 64 + lane];
    float2 v1 = h2[(size_t)q0.z * 64 + lane];
    float2 v2 = h2[(size_t)q1.x * 64 + lane];
    float2 v3 = h2[(size_t)q1.z * 64 + lane];
    float2 v4 = h2[(size_t)q2.x * 64 + lane];
    float2 v5 = h2[(size_t)q2.z * 64 + lane];
    float2 v6 = h2[(size_t)q3.x * 64 + lane];
    float2 v7 = h2[(size_t)q3.z * 64 + lane];
    float f0 = __int_as_float(q0.y), f1 = __int_as_float(q0.w);
    float f2 = __int_as_float(q1.y), f3 = __int_as_float(q1.w);
    float f4 = __int_as_float(q2.y), f5 = __int_as_float(q2.w);
    float f6 = __int_as_float(q3.y), f7 = __int_as_float(q3.w);
    ax += v0.x * f0; ay += v0.y * f0;
    ax += v1.x * f1; ay += v1.y * f1;
    ax += v2.x * f2; ay += v2.y * f2;
    ax += v3.x * f3; ay += v3.y * f3;
    ax += v4.x * f4; ay += v4.y * f4;
    ax += v5.x * f5; ay += v5.y * f5;
    ax += v6.x * f6; ay += v6.y * f6;
    ax += v7.x * f7; ay += v7.y * f7;
  }
  for (; i + 2 <= e; i += 2) {
    int4 q = cp4[i >> 1];
    float2 v0 = h2[(size_t)q.x * 64 + lane];
    float2 v1 = h2[(size_t)q.z * 64 + lane];
    float f0 = __int_as_float(q.y), f1 = __int_as_float(q.w);
    ax += v0.x * f0; ay += v0.y * f0;
    ax += v1.x * f1; ay += v1.y * f1;
  }
  if (i < e) {
    int2 p = csr_pair[i];
    float2 v = h2[(size_t)p.x * 64 + lane];
    float f = __int_as_float(p.y);
    ax += v.x * f; ay += v.y * f;
  }
  return float2{ax, ay};
}

__global__ __launch_bounds__(256) void k_agg(const float* __restrict__ h,
                                             const int* __restrict__ offs,
                                             const int2* __restrict__ csr_pair,
                                             const float* __restrict__ dinv,
                                             const float* __restrict__ bias,
                                             float* __restrict__ out,
                                             int n, int relu) {
  int node = blockIdx.x * 4 + (threadIdx.x >> 6);
  if (node >= n) return;
  int lane = threadIdx.x & 63;
  float2 r = gather_node((const float2*)h, offs, csr_pair, dinv, node, lane);
  float2 bb = ((const float2*)bias)[lane];
  float ax = r.x + bb.x, ay = r.y + bb.y;
  if (relu) { ax = fmaxf(ax, 0.f); ay = fmaxf(ay, 0.f); }
  ((float2*)out)[(size_t)node * 64 + lane] = float2{ax, ay};
}

// Layer-4 agg fused with mean-pool accumulation (W3/b3 applied post-pool).
__global__ __launch_bounds__(256) void k_agg_pool(const float* __restrict__ h,
                                                  const int* __restrict__ offs,
                                                  const int2* __restrict__ csr_pair,
                                                  const float* __restrict__ dinv,
                                                  const void* __restrict__ batch,
                                                  float* __restrict__ sums,
                                                  float* __restrict__ cnts,
                                                  int n, const int* __restrict__ flag) {
  int node = blockIdx.x * 4 + (threadIdx.x >> 6);
  if (node >= n) return;
  int lane = threadIdx.x & 63;
  float2 r = gather_node((const float2*)h, offs, csr_pair, dinv, node, lane);
  int g = idx_at(batch, node, *flag);
  atomicAdd(&sums[g * 128 + lane * 2], r.x);
  atomicAdd(&sums[g * 128 + lane * 2 + 1], r.y);
  if (lane == 0) atomicAdd(&cnts[g], 1.0f);
}

// pooled = sums/cnt; t1 = pooled@W3+b3; logits = t1@Wlin+blin; softmax.
__global__ __launch_bounds__(128) void k_final(const float* __restrict__ sums,
                                               const float* __restrict__ cnts,
                                               const float* __restrict__ W3,
                                               const float* __restrict__ b3,
                                               const float* __restrict__ Wlin,
                                               const float* __restrict__ blin,
                                               float* __restrict__ out) {
  __shared__ float p[128];
  __shared__ float t1[128];
  __shared__ float lg[16];
  int g = blockIdx.x;
  int t = threadIdx.x;
  float inv = 1.f / fmaxf(cnts[g], 1.f);
  p[t] = sums[g * 128 + t] * inv;
  __syncthreads();
  float acc = 0.f;
  for (int k = 0; k < 128; k++) acc += p[k] * W3[k * 128 + t];
  t1[t] = acc + b3[t];
  __syncthreads();
  if (t < 16) {
    float a2 = 0.f;
    for (int k = 0; k < 128; k++) a2 += t1[k] * Wlin[k * 16 + t];
    lg[t] = a2 + blin[t];
  }
  __syncthreads();
  if (t < 16) {
    float m = -1e30f;
    for (int j = 0; j < 16; j++) m = fmaxf(m, lg[j]);
    float s = 0.f;
    for (int j = 0; j < 16; j++) s += expf(lg[j] - m);
    out[g * 16 + t] = expf(lg[t] - m) / s;
  }
}

extern "C" void kernel_launch(void* const* d_in, const int* in_sizes, int n_in,
                              void* d_out, int out_size, void* d_ws, size_t ws_size,
                              hipStream_t stream) {
  const float* x = (const float*)d_in[0];
  const void* edge = d_in[1];
  const void* batch = d_in[2];
  const float* W[4] = {(const float*)d_in[3], (const float*)d_in[5],
                       (const float*)d_in[7], (const float*)d_in[9]};
  const float* b[4] = {(const float*)d_in[4], (const float*)d_in[6],
                       (const float*)d_in[8], (const float*)d_in[10]};
  const float* Wlin = (const float*)d_in[11];
  const float* blin = (const float*)d_in[12];
  float* out = (float*)d_out;

  int n = in_sizes[0] / 128;
  int E = in_sizes[1] / 2;
  int ngraphs = out_size / 16;

  char* ws = (char*)d_ws;
  size_t off = 0;
  auto alloc = [&](size_t bytes) -> void* {
    void* p = ws + off;
    off = (off + bytes + 255) & ~(size_t)255;
    return p;
  };
  int* flag = (int*)alloc(4);
  int* cnt = (int*)alloc((size_t)n * 4);
  int* offs = (int*)alloc((size_t)(n + 1) * 4);
  int* cursor = (int*)alloc((size_t)n * 4);
  float* dinv = (float*)alloc((size_t)n * 4);
  int* bsum = (int*)alloc(1024 * 4);
  int2* csr_pair = (int2*)alloc((size_t)E * 8);
  float* bufA = (float*)alloc((size_t)n * 128 * 4);
  float* bufB = (float*)alloc((size_t)n * 128 * 4);
  float* sums = (float*)alloc((size_t)ngraphs * 128 * 4);
  float* cnts = (float*)alloc((size_t)ngraphs * 4);

  hipMemsetAsync(cnt, 0, (size_t)n * 4, stream);
  hipMemsetAsync(sums, 0, (size_t)ngraphs * 128 * 4, stream);
  hipMemsetAsync(cnts, 0, (size_t)ngraphs * 4, stream);
  k_detect<<<1, 64, 0, stream>>>((const int*)edge, flag);
  k_count<<<(E + 255) / 256, 256, 0, stream>>>(edge, E, cnt, flag);
  k_dinv<<<(n + 255) / 256, 256, 0, stream>>>(cnt, n, dinv);
  int nb = (n + 255) / 256;
  k_scan1<<<nb, 256, 0, stream>>>(cnt, offs, bsum, n);
  k_scan2<<<1, 256, 0, stream>>>(bsum, nb);
  k_scan3<<<nb, 256, 0, stream>>>(offs, cursor, bsum, n, E);
  k_fill<<<(E + 255) / 256, 256, 0, stream>>>(edge, E, dinv, cursor, csr_pair, flag);

  int ntiles = (n + GR - 1) / GR;
  const float* cur = x;
  for (int l = 0; l < 3; l++) {
    k_gemm<<<512, 256, 0, stream>>>(cur, W[l], bufA, n, ntiles);
    k_agg<<<(n + 3) / 4, 256, 0, stream>>>(bufA, offs, csr_pair, dinv,
                                           b[l], bufB, n, 1);
    cur = bufB;
  }
  k_agg_pool<<<(n + 3) / 4, 256, 0, stream>>>(bufB, offs, csr_pair, dinv,
                                              batch, sums, cnts, n, flag);
  k_final<<<ngraphs, 128, 0, stream>>>(sums, cnts, W[3], b[3], Wlin, blin, out);
}

// Round 5
// 436.818 us; speedup vs baseline: 1.7901x; 1.7901x over previous
//
#include <hip/hip_runtime.h>

// ---------------------------------------------------------------------------
// GCN forward: 3x (GEMM 50000x128x128 + CSR agg) + layer-4 agg + chunked pool
// (W3 commuted past the mean-pool) + fused final linear chain + softmax. fp32.
// ---------------------------------------------------------------------------

__device__ __forceinline__ int idx_at(const void* p, long long i, int is64) {
  return is64 ? (int)((const long long*)p)[i] : ((const int*)p)[i];
}

__global__ void k_detect(const int* __restrict__ edge, int* __restrict__ flag) {
  if (threadIdx.x == 0 && blockIdx.x == 0) {
    int all0 = 1;
    for (int i = 1; i < 128; i += 2)
      if (edge[i] != 0) { all0 = 0; break; }
    *flag = all0;
  }
}

__global__ void k_count(const void* __restrict__ edge, int E,
                        int* __restrict__ cnt, const int* __restrict__ flag) {
  int e = blockIdx.x * 256 + threadIdx.x;
  int is64 = *flag;
  if (e < E) {
    int c = idx_at(edge, (long long)E + e, is64);  // col = target
    atomicAdd(&cnt[c], 1);
  }
}

__global__ void k_dinv(const int* __restrict__ cnt, int n, float* __restrict__ dinv) {
  int i = blockIdx.x * 256 + threadIdx.x;
  if (i < n) dinv[i] = rsqrtf((float)(cnt[i] + 1));  // +1 self loop
}

// --- 3-kernel exclusive scan over cnt[n] -> offs[n] -------------------------
__global__ void k_scan1(const int* __restrict__ cnt, int* __restrict__ offs,
                        int* __restrict__ bsum, int n) {
  __shared__ int lds[256];
  int i = blockIdx.x * 256 + threadIdx.x;
  int v = (i < n) ? cnt[i] : 0;
  lds[threadIdx.x] = v;
  __syncthreads();
  for (int off = 1; off < 256; off <<= 1) {
    int t = (threadIdx.x >= off) ? lds[threadIdx.x - off] : 0;
    __syncthreads();
    lds[threadIdx.x] += t;
    __syncthreads();
  }
  if (i < n) offs[i] = lds[threadIdx.x] - v;
  if (threadIdx.x == 255) bsum[blockIdx.x] = lds[255];
}

__global__ void k_scan2(int* __restrict__ bsum, int nb) {
  __shared__ int lds[256];
  int v = (threadIdx.x < nb) ? bsum[threadIdx.x] : 0;
  lds[threadIdx.x] = v;
  __syncthreads();
  for (int off = 1; off < 256; off <<= 1) {
    int t = (threadIdx.x >= off) ? lds[threadIdx.x - off] : 0;
    __syncthreads();
    lds[threadIdx.x] += t;
    __syncthreads();
  }
  if (threadIdx.x < nb) bsum[threadIdx.x] = lds[threadIdx.x] - v;
}

__global__ void k_scan3(int* __restrict__ offs, int* __restrict__ cursor,
                        const int* __restrict__ bsum, int n, int E) {
  int i = blockIdx.x * 256 + threadIdx.x;
  if (i < n) {
    int o = offs[i] + bsum[blockIdx.x];
    offs[i] = o;
    cursor[i] = o;
  }
  if (i == 0) offs[n] = E;
}

// csr_pair[p] = {source_row, bitcast(norm)}
__global__ void k_fill(const void* __restrict__ edge, int E,
                       const float* __restrict__ dinv, int* __restrict__ cursor,
                       int2* __restrict__ csr_pair, const int* __restrict__ flag) {
  int e = blockIdx.x * 256 + threadIdx.x;
  int is64 = *flag;
  if (e < E) {
    int r = idx_at(edge, e, is64);
    int c = idx_at(edge, (long long)E + e, is64);
    int p = atomicAdd(&cursor[c], 1);
    float nm = dinv[r] * dinv[c];
    csr_pair[p] = int2{r, __float_as_int(nm)};
  }
}

// --- GEMM: C[n x 128] = A[n x 128] @ W[128 x 128] ---------------------------
// Tile 128 rows x 64 cols. Only the block's W col-half (32 KB) in LDS ->
// 4 blocks/CU = 4 waves/SIMD. A streamed from global (16-lane broadcast).
#define RT 128
__global__ __launch_bounds__(256) void k_gemm(const float* __restrict__ A,
                                              const float* __restrict__ W,
                                              float* __restrict__ C, int n) {
  __shared__ float4 Wl[128 * 16];  // 32 KB: Wl[k][c4] for this col-half
  int b = blockIdx.x;
  int row_tile = b >> 1, ch = b & 1;
  const float4* W4 = (const float4*)W;
  const float4* A4 = (const float4*)A;
  float4* C4 = (float4*)C;
  int t = threadIdx.x;
#pragma unroll
  for (int j = 0; j < 8; j++) {
    int f = t + 256 * j;  // 0..2047
    int row = f >> 4, c = f & 15;
    Wl[f] = W4[row * 32 + ch * 16 + c];
  }
  __syncthreads();
  int tr = t >> 4;   // 0..15 (row group of 8)
  int tc4 = t & 15;  // float4 col within half
  int r0 = row_tile * RT + tr * 8;
  const float4* ap[8];
#pragma unroll
  for (int ii = 0; ii < 8; ii++) {
    int rr = r0 + ii;
    if (rr > n - 1) rr = n - 1;  // clamp: safe load, store guarded below
    ap[ii] = A4 + (size_t)rr * 32;
  }
  float4 acc[8];
#pragma unroll
  for (int ii = 0; ii < 8; ii++) acc[ii] = float4{0, 0, 0, 0};
#pragma unroll 4
  for (int k4 = 0; k4 < 32; k4++) {
    float4 w0 = Wl[(4 * k4 + 0) * 16 + tc4];
    float4 w1 = Wl[(4 * k4 + 1) * 16 + tc4];
    float4 w2 = Wl[(4 * k4 + 2) * 16 + tc4];
    float4 w3 = Wl[(4 * k4 + 3) * 16 + tc4];
#pragma unroll
    for (int ii = 0; ii < 8; ii++) {
      float4 a = ap[ii][k4];
      acc[ii].x += a.x * w0.x + a.y * w1.x + a.z * w2.x + a.w * w3.x;
      acc[ii].y += a.x * w0.y + a.y * w1.y + a.z * w2.y + a.w * w3.y;
      acc[ii].z += a.x * w0.z + a.y * w1.z + a.z * w2.z + a.w * w3.z;
      acc[ii].w += a.x * w0.w + a.y * w1.w + a.z * w2.w + a.w * w3.w;
    }
  }
#pragma unroll
  for (int ii = 0; ii < 8; ii++) {
    int gr = r0 + ii;
    if (gr < n) C4[(size_t)gr * 32 + ch * 16 + tc4] = acc[ii];
  }
}

// --- Gather core: one wave per node, 2 floats/lane, 8-deep pipeline ---------
__device__ __forceinline__ float2 gather_node(const float2* __restrict__ h2,
                                              const int* __restrict__ offs,
                                              const int2* __restrict__ csr_pair,
                                              const float* __restrict__ dinv,
                                              int node, int lane) {
  int s = offs[node], e = offs[node + 1];
  float dn = dinv[node];
  float2 self = h2[(size_t)node * 64 + lane];
  float ax = self.x * dn * dn;
  float ay = self.y * dn * dn;
  int i = s;
  if ((i & 1) && i < e) {  // align to int4 pairs
    int2 p = csr_pair[i];
    float2 v = h2[(size_t)p.x * 64 + lane];
    float f = __int_as_float(p.y);
    ax += v.x * f; ay += v.y * f;
    i++;
  }
  const int4* cp4 = (const int4*)csr_pair;
  for (; i + 8 <= e; i += 8) {
    int4 q0 = cp4[(i >> 1) + 0];
    int4 q1 = cp4[(i >> 1) + 1];
    int4 q2 = cp4[(i >> 1) + 2];
    int4 q3 = cp4[(i >> 1) + 3];
    float2 v0 = h2[(size_t)q0.x * 64 + lane];
    float2 v1 = h2[(size_t)q0.z * 64 + lane];
    float2 v2 = h2[(size_t)q1.x * 64 + lane];
    float2 v3 = h2[(size_t)q1.z * 64 + lane];
    float2 v4 = h2[(size_t)q2.x * 64 + lane];
    float2 v5 = h2[(size_t)q2.z * 64 + lane];
    float2 v6 = h2[(size_t)q3.x * 64 + lane];
    float2 v7 = h2[(size_t)q3.z * 64 + lane];
    float f0 = __int_as_float(q0.y), f1 = __int_as_float(q0.w);
    float f2 = __int_as_float(q1.y), f3 = __int_as_float(q1.w);
    float f4 = __int_as_float(q2.y), f5 = __int_as_float(q2.w);
    float f6 = __int_as_float(q3.y), f7 = __int_as_float(q3.w);
    ax += v0.x * f0; ay += v0.y * f0;
    ax += v1.x * f1; ay += v1.y * f1;
    ax += v2.x * f2; ay += v2.y * f2;
    ax += v3.x * f3; ay += v3.y * f3;
    ax += v4.x * f4; ay += v4.y * f4;
    ax += v5.x * f5; ay += v5.y * f5;
    ax += v6.x * f6; ay += v6.y * f6;
    ax += v7.x * f7; ay += v7.y * f7;
  }
  for (; i + 2 <= e; i += 2) {
    int4 q = cp4[i >> 1];
    float2 v0 = h2[(size_t)q.x * 64 + lane];
    float2 v1 = h2[(size_t)q.z * 64 + lane];
    float f0 = __int_as_float(q.y), f1 = __int_as_float(q.w);
    ax += v0.x * f0; ay += v0.y * f0;
    ax += v1.x * f1; ay += v1.y * f1;
  }
  if (i < e) {
    int2 p = csr_pair[i];
    float2 v = h2[(size_t)p.x * 64 + lane];
    float f = __int_as_float(p.y);
    ax += v.x * f; ay += v.y * f;
  }
  return float2{ax, ay};
}

__global__ __launch_bounds__(256) void k_agg(const float* __restrict__ h,
                                             const int* __restrict__ offs,
                                             const int2* __restrict__ csr_pair,
                                             const float* __restrict__ dinv,
                                             const float* __restrict__ bias,
                                             float* __restrict__ out,
                                             int n, int relu) {
  int node = blockIdx.x * 4 + (threadIdx.x >> 6);
  if (node >= n) return;
  int lane = threadIdx.x & 63;
  float2 r = gather_node((const float2*)h, offs, csr_pair, dinv, node, lane);
  float ax = r.x, ay = r.y;
  if (bias) {
    float2 bb = ((const float2*)bias)[lane];
    ax += bb.x; ay += bb.y;
  }
  if (relu) { ax = fmaxf(ax, 0.f); ay = fmaxf(ay, 0.f); }
  ((float2*)out)[(size_t)node * 64 + lane] = float2{ax, ay};
}

// --- Mean pool: chunked partial sums + atomics (batch sorted) ---------------
#define POOL_CH 64
__global__ __launch_bounds__(128) void k_pool_partial(
    const float* __restrict__ h, const void* __restrict__ batch, int n,
    float* __restrict__ sums, float* __restrict__ cnts,
    const int* __restrict__ flag) {
  int start = blockIdx.x * POOL_CH;
  if (start >= n) return;
  int end = start + POOL_CH;
  if (end > n) end = n;
  int f = threadIdx.x;  // 128 feature lanes
  int is64 = *flag;
  int g = idx_at(batch, start, is64);
  float acc = 0.f, c = 0.f;
  for (int i = start; i < end; i++) {
    int gi = idx_at(batch, i, is64);
    if (gi != g) {
      atomicAdd(&sums[g * 128 + f], acc);
      if (f == 0) atomicAdd(&cnts[g], c);
      acc = 0.f; c = 0.f; g = gi;
    }
    acc += h[(size_t)i * 128 + f];
    c += 1.f;
  }
  atomicAdd(&sums[g * 128 + f], acc);
  if (f == 0) atomicAdd(&cnts[g], c);
}

// pooled = sums/cnt; t1 = pooled@W3+b3; logits = t1@Wlin+blin; softmax.
__global__ __launch_bounds__(128) void k_final(const float* __restrict__ sums,
                                               const float* __restrict__ cnts,
                                               const float* __restrict__ W3,
                                               const float* __restrict__ b3,
                                               const float* __restrict__ Wlin,
                                               const float* __restrict__ blin,
                                               float* __restrict__ out) {
  __shared__ float p[128];
  __shared__ float t1[128];
  __shared__ float lg[16];
  int g = blockIdx.x;
  int t = threadIdx.x;
  float inv = 1.f / fmaxf(cnts[g], 1.f);
  p[t] = sums[g * 128 + t] * inv;
  __syncthreads();
  float acc = 0.f;
  for (int k = 0; k < 128; k++) acc += p[k] * W3[k * 128 + t];
  t1[t] = acc + b3[t];
  __syncthreads();
  if (t < 16) {
    float a2 = 0.f;
    for (int k = 0; k < 128; k++) a2 += t1[k] * Wlin[k * 16 + t];
    lg[t] = a2 + blin[t];
  }
  __syncthreads();
  if (t < 16) {
    float m = -1e30f;
    for (int j = 0; j < 16; j++) m = fmaxf(m, lg[j]);
    float s = 0.f;
    for (int j = 0; j < 16; j++) s += expf(lg[j] - m);
    out[g * 16 + t] = expf(lg[t] - m) / s;
  }
}

extern "C" void kernel_launch(void* const* d_in, const int* in_sizes, int n_in,
                              void* d_out, int out_size, void* d_ws, size_t ws_size,
                              hipStream_t stream) {
  const float* x = (const float*)d_in[0];
  const void* edge = d_in[1];
  const void* batch = d_in[2];
  const float* W[4] = {(const float*)d_in[3], (const float*)d_in[5],
                       (const float*)d_in[7], (const float*)d_in[9]};
  const float* b[4] = {(const float*)d_in[4], (const float*)d_in[6],
                       (const float*)d_in[8], (const float*)d_in[10]};
  const float* Wlin = (const float*)d_in[11];
  const float* blin = (const float*)d_in[12];
  float* out = (float*)d_out;

  int n = in_sizes[0] / 128;
  int E = in_sizes[1] / 2;
  int ngraphs = out_size / 16;

  char* ws = (char*)d_ws;
  size_t off = 0;
  auto alloc = [&](size_t bytes) -> void* {
    void* p = ws + off;
    off = (off + bytes + 255) & ~(size_t)255;
    return p;
  };
  int* flag = (int*)alloc(4);
  int* cnt = (int*)alloc((size_t)n * 4);
  int* offs = (int*)alloc((size_t)(n + 1) * 4);
  int* cursor = (int*)alloc((size_t)n * 4);
  float* dinv = (float*)alloc((size_t)n * 4);
  int* bsum = (int*)alloc(1024 * 4);
  int2* csr_pair = (int2*)alloc((size_t)E * 8);
  float* bufA = (float*)alloc((size_t)n * 128 * 4);
  float* bufB = (float*)alloc((size_t)n * 128 * 4);
  float* sums = (float*)alloc((size_t)ngraphs * 128 * 4);
  float* cnts = (float*)alloc((size_t)ngraphs * 4);

  hipMemsetAsync(cnt, 0, (size_t)n * 4, stream);
  hipMemsetAsync(sums, 0, (size_t)ngraphs * 128 * 4, stream);
  hipMemsetAsync(cnts, 0, (size_t)ngraphs * 4, stream);
  k_detect<<<1, 64, 0, stream>>>((const int*)edge, flag);
  k_count<<<(E + 255) / 256, 256, 0, stream>>>(edge, E, cnt, flag);
  k_dinv<<<(n + 255) / 256, 256, 0, stream>>>(cnt, n, dinv);
  int nb = (n + 255) / 256;
  k_scan1<<<nb, 256, 0, stream>>>(cnt, offs, bsum, n);
  k_scan2<<<1, 256, 0, stream>>>(bsum, nb);
  k_scan3<<<nb, 256, 0, stream>>>(offs, cursor, bsum, n, E);
  k_fill<<<(E + 255) / 256, 256, 0, stream>>>(edge, E, dinv, cursor, csr_pair, flag);

  int nrt = (n + RT - 1) / RT;
  const float* cur = x;
  for (int l = 0; l < 3; l++) {
    k_gemm<<<nrt * 2, 256, 0, stream>>>(cur, W[l], bufA, n);
    k_agg<<<(n + 3) / 4, 256, 0, stream>>>(bufA, offs, csr_pair, dinv,
                                           b[l], bufB, n, 1);
    cur = bufB;
  }
  // layer 4: agg only (no bias, no relu); W3+b3 applied post-pool in k_final
  k_agg<<<(n + 3) / 4, 256, 0, stream>>>(bufB, offs, csr_pair, dinv,
                                         nullptr, bufA, n, 0);
  k_pool_partial<<<(n + POOL_CH - 1) / POOL_CH, 128, 0, stream>>>(bufA, batch, n, sums, cnts, flag);
  k_final<<<ngraphs, 128, 0, stream>>>(sums, cnts, W[3], b[3], Wlin, blin, out);
}

// Round 6
// 363.468 us; speedup vs baseline: 2.1513x; 1.2018x over previous
//
#include <hip/hip_runtime.h>
#include <hip/hip_fp16.h>

// ---------------------------------------------------------------------------
// GCN forward: 3x (GEMM 50000x128x128 -> fp16 h + CSR agg) + layer-4 agg +
// chunked pool (W3 commuted past mean-pool) + fused final chain + softmax.
// Intermediate node features stored fp16; all arithmetic fp32.
// ---------------------------------------------------------------------------

__device__ __forceinline__ int idx_at(const void* p, long long i, int is64) {
  return is64 ? (int)((const long long*)p)[i] : ((const int*)p)[i];
}

__global__ void k_detect(const int* __restrict__ edge, int* __restrict__ flag) {
  if (threadIdx.x == 0 && blockIdx.x == 0) {
    int all0 = 1;
    for (int i = 1; i < 128; i += 2)
      if (edge[i] != 0) { all0 = 0; break; }
    *flag = all0;
  }
}

__global__ void k_count(const void* __restrict__ edge, int E,
                        int* __restrict__ cnt, const int* __restrict__ flag) {
  int e = blockIdx.x * 256 + threadIdx.x;
  int is64 = *flag;
  if (e < E) {
    int c = idx_at(edge, (long long)E + e, is64);  // col = target
    atomicAdd(&cnt[c], 1);
  }
}

__global__ void k_dinv(const int* __restrict__ cnt, int n, float* __restrict__ dinv) {
  int i = blockIdx.x * 256 + threadIdx.x;
  if (i < n) dinv[i] = rsqrtf((float)(cnt[i] + 1));  // +1 self loop
}

// --- 3-kernel exclusive scan over cnt[n] -> offs[n] -------------------------
__global__ void k_scan1(const int* __restrict__ cnt, int* __restrict__ offs,
                        int* __restrict__ bsum, int n) {
  __shared__ int lds[256];
  int i = blockIdx.x * 256 + threadIdx.x;
  int v = (i < n) ? cnt[i] : 0;
  lds[threadIdx.x] = v;
  __syncthreads();
  for (int off = 1; off < 256; off <<= 1) {
    int t = (threadIdx.x >= off) ? lds[threadIdx.x - off] : 0;
    __syncthreads();
    lds[threadIdx.x] += t;
    __syncthreads();
  }
  if (i < n) offs[i] = lds[threadIdx.x] - v;
  if (threadIdx.x == 255) bsum[blockIdx.x] = lds[255];
}

__global__ void k_scan2(int* __restrict__ bsum, int nb) {
  __shared__ int lds[256];
  int v = (threadIdx.x < nb) ? bsum[threadIdx.x] : 0;
  lds[threadIdx.x] = v;
  __syncthreads();
  for (int off = 1; off < 256; off <<= 1) {
    int t = (threadIdx.x >= off) ? lds[threadIdx.x - off] : 0;
    __syncthreads();
    lds[threadIdx.x] += t;
    __syncthreads();
  }
  if (threadIdx.x < nb) bsum[threadIdx.x] = lds[threadIdx.x] - v;
}

__global__ void k_scan3(int* __restrict__ offs, int* __restrict__ cursor,
                        const int* __restrict__ bsum, int n, int E) {
  int i = blockIdx.x * 256 + threadIdx.x;
  if (i < n) {
    int o = offs[i] + bsum[blockIdx.x];
    offs[i] = o;
    cursor[i] = o;
  }
  if (i == 0) offs[n] = E;
}

// csr_pair[p] = {source_row, bitcast(norm)}
__global__ void k_fill(const void* __restrict__ edge, int E,
                       const float* __restrict__ dinv, int* __restrict__ cursor,
                       int2* __restrict__ csr_pair, const int* __restrict__ flag) {
  int e = blockIdx.x * 256 + threadIdx.x;
  int is64 = *flag;
  if (e < E) {
    int r = idx_at(edge, e, is64);
    int c = idx_at(edge, (long long)E + e, is64);
    int p = atomicAdd(&cursor[c], 1);
    float nm = dinv[r] * dinv[c];
    csr_pair[p] = int2{r, __float_as_int(nm)};
  }
}

// --- GEMM: C16[n x 128](fp16) = A[n x 128](fp32) @ W[128 x 128] -------------
// Tile 128 rows x 64 cols. W col-half (32 KB) in LDS -> 4 blocks/CU.
#define RT 128
__global__ __launch_bounds__(256) void k_gemm(const float* __restrict__ A,
                                              const float* __restrict__ W,
                                              uint2* __restrict__ C16, int n) {
  __shared__ float4 Wl[128 * 16];  // 32 KB: Wl[k][c4] for this col-half
  int b = blockIdx.x;
  int row_tile = b >> 1, ch = b & 1;
  const float4* W4 = (const float4*)W;
  const float4* A4 = (const float4*)A;
  int t = threadIdx.x;
#pragma unroll
  for (int j = 0; j < 8; j++) {
    int f = t + 256 * j;  // 0..2047
    int row = f >> 4, c = f & 15;
    Wl[f] = W4[row * 32 + ch * 16 + c];
  }
  __syncthreads();
  int tr = t >> 4;   // 0..15 (row group of 8)
  int tc4 = t & 15;  // float4 col within half
  int r0 = row_tile * RT + tr * 8;
  const float4* ap[8];
#pragma unroll
  for (int ii = 0; ii < 8; ii++) {
    int rr = r0 + ii;
    if (rr > n - 1) rr = n - 1;  // clamp: safe load, store guarded below
    ap[ii] = A4 + (size_t)rr * 32;
  }
  float4 acc[8];
#pragma unroll
  for (int ii = 0; ii < 8; ii++) acc[ii] = float4{0, 0, 0, 0};
#pragma unroll 4
  for (int k4 = 0; k4 < 32; k4++) {
    float4 w0 = Wl[(4 * k4 + 0) * 16 + tc4];
    float4 w1 = Wl[(4 * k4 + 1) * 16 + tc4];
    float4 w2 = Wl[(4 * k4 + 2) * 16 + tc4];
    float4 w3 = Wl[(4 * k4 + 3) * 16 + tc4];
#pragma unroll
    for (int ii = 0; ii < 8; ii++) {
      float4 a = ap[ii][k4];
      acc[ii].x += a.x * w0.x + a.y * w1.x + a.z * w2.x + a.w * w3.x;
      acc[ii].y += a.x * w0.y + a.y * w1.y + a.z * w2.y + a.w * w3.y;
      acc[ii].z += a.x * w0.z + a.y * w1.z + a.z * w2.z + a.w * w3.z;
      acc[ii].w += a.x * w0.w + a.y * w1.w + a.z * w2.w + a.w * w3.w;
    }
  }
#pragma unroll
  for (int ii = 0; ii < 8; ii++) {
    int gr = r0 + ii;
    if (gr < n) {
      union { __half2 h2[2]; uint2 u; } cv;
      cv.h2[0] = __floats2half2_rn(acc[ii].x, acc[ii].y);
      cv.h2[1] = __floats2half2_rn(acc[ii].z, acc[ii].w);
      C16[(size_t)gr * 32 + ch * 16 + tc4] = cv.u;
    }
  }
}

// --- Gather core: one wave per node, one half2/lane, 8-deep pipeline --------
__device__ __forceinline__ float2 gather16(const __half2* __restrict__ h16,
                                           const int* __restrict__ offs,
                                           const int2* __restrict__ csr_pair,
                                           const float* __restrict__ dinv,
                                           int node, int lane) {
  int s = offs[node], e = offs[node + 1];
  float dn = dinv[node];
  float2 self = __half22float2(h16[(size_t)node * 64 + lane]);
  float ax = self.x * dn * dn;
  float ay = self.y * dn * dn;
  int i = s;
  if ((i & 1) && i < e) {  // align to int4 pairs
    int2 p = csr_pair[i];
    float2 v = __half22float2(h16[(size_t)p.x * 64 + lane]);
    float f = __int_as_float(p.y);
    ax += v.x * f; ay += v.y * f;
    i++;
  }
  const int4* cp4 = (const int4*)csr_pair;
  for (; i + 8 <= e; i += 8) {
    int4 q0 = cp4[(i >> 1) + 0];
    int4 q1 = cp4[(i >> 1) + 1];
    int4 q2 = cp4[(i >> 1) + 2];
    int4 q3 = cp4[(i >> 1) + 3];
    float2 v0 = __half22float2(h16[(size_t)q0.x * 64 + lane]);
    float2 v1 = __half22float2(h16[(size_t)q0.z * 64 + lane]);
    float2 v2 = __half22float2(h16[(size_t)q1.x * 64 + lane]);
    float2 v3 = __half22float2(h16[(size_t)q1.z * 64 + lane]);
    float2 v4 = __half22float2(h16[(size_t)q2.x * 64 + lane]);
    float2 v5 = __half22float2(h16[(size_t)q2.z * 64 + lane]);
    float2 v6 = __half22float2(h16[(size_t)q3.x * 64 + lane]);
    float2 v7 = __half22float2(h16[(size_t)q3.z * 64 + lane]);
    float f0 = __int_as_float(q0.y), f1 = __int_as_float(q0.w);
    float f2 = __int_as_float(q1.y), f3 = __int_as_float(q1.w);
    float f4 = __int_as_float(q2.y), f5 = __int_as_float(q2.w);
    float f6 = __int_as_float(q3.y), f7 = __int_as_float(q3.w);
    ax += v0.x * f0; ay += v0.y * f0;
    ax += v1.x * f1; ay += v1.y * f1;
    ax += v2.x * f2; ay += v2.y * f2;
    ax += v3.x * f3; ay += v3.y * f3;
    ax += v4.x * f4; ay += v4.y * f4;
    ax += v5.x * f5; ay += v5.y * f5;
    ax += v6.x * f6; ay += v6.y * f6;
    ax += v7.x * f7; ay += v7.y * f7;
  }
  for (; i + 2 <= e; i += 2) {
    int4 q = cp4[i >> 1];
    float2 v0 = __half22float2(h16[(size_t)q.x * 64 + lane]);
    float2 v1 = __half22float2(h16[(size_t)q.z * 64 + lane]);
    float f0 = __int_as_float(q.y), f1 = __int_as_float(q.w);
    ax += v0.x * f0; ay += v0.y * f0;
    ax += v1.x * f1; ay += v1.y * f1;
  }
  if (i < e) {
    int2 p = csr_pair[i];
    float2 v = __half22float2(h16[(size_t)p.x * 64 + lane]);
    float f = __int_as_float(p.y);
    ax += v.x * f; ay += v.y * f;
  }
  return float2{ax, ay};
}

// out32 and/or out16 may be null.
__global__ __launch_bounds__(256) void k_agg(const __half2* __restrict__ h16,
                                             const int* __restrict__ offs,
                                             const int2* __restrict__ csr_pair,
                                             const float* __restrict__ dinv,
                                             const float* __restrict__ bias,
                                             float* __restrict__ out32,
                                             __half2* __restrict__ out16,
                                             int n, int relu) {
  int node = blockIdx.x * 4 + (threadIdx.x >> 6);
  if (node >= n) return;
  int lane = threadIdx.x & 63;
  float2 r = gather16(h16, offs, csr_pair, dinv, node, lane);
  float ax = r.x, ay = r.y;
  if (bias) {
    float2 bb = ((const float2*)bias)[lane];
    ax += bb.x; ay += bb.y;
  }
  if (relu) { ax = fmaxf(ax, 0.f); ay = fmaxf(ay, 0.f); }
  if (out32) ((float2*)out32)[(size_t)node * 64 + lane] = float2{ax, ay};
  if (out16) out16[(size_t)node * 64 + lane] = __floats2half2_rn(ax, ay);
}

// --- Mean pool: chunked partial sums + atomics (batch sorted) ---------------
#define POOL_CH 64
__global__ __launch_bounds__(128) void k_pool_partial(
    const float* __restrict__ h, const void* __restrict__ batch, int n,
    float* __restrict__ sums, float* __restrict__ cnts,
    const int* __restrict__ flag) {
  int start = blockIdx.x * POOL_CH;
  if (start >= n) return;
  int end = start + POOL_CH;
  if (end > n) end = n;
  int f = threadIdx.x;  // 128 feature lanes
  int is64 = *flag;
  int g = idx_at(batch, start, is64);
  float acc = 0.f, c = 0.f;
  for (int i = start; i < end; i++) {
    int gi = idx_at(batch, i, is64);
    if (gi != g) {
      atomicAdd(&sums[g * 128 + f], acc);
      if (f == 0) atomicAdd(&cnts[g], c);
      acc = 0.f; c = 0.f; g = gi;
    }
    acc += h[(size_t)i * 128 + f];
    c += 1.f;
  }
  atomicAdd(&sums[g * 128 + f], acc);
  if (f == 0) atomicAdd(&cnts[g], c);
}

// pooled = sums/cnt; t1 = pooled@W3+b3; logits = t1@Wlin+blin; softmax.
__global__ __launch_bounds__(128) void k_final(const float* __restrict__ sums,
                                               const float* __restrict__ cnts,
                                               const float* __restrict__ W3,
                                               const float* __restrict__ b3,
                                               const float* __restrict__ Wlin,
                                               const float* __restrict__ blin,
                                               float* __restrict__ out) {
  __shared__ float p[128];
  __shared__ float t1[128];
  __shared__ float lg[16];
  int g = blockIdx.x;
  int t = threadIdx.x;
  float inv = 1.f / fmaxf(cnts[g], 1.f);
  p[t] = sums[g * 128 + t] * inv;
  __syncthreads();
  float acc = 0.f;
  for (int k = 0; k < 128; k++) acc += p[k] * W3[k * 128 + t];
  t1[t] = acc + b3[t];
  __syncthreads();
  if (t < 16) {
    float a2 = 0.f;
    for (int k = 0; k < 128; k++) a2 += t1[k] * Wlin[k * 16 + t];
    lg[t] = a2 + blin[t];
  }
  __syncthreads();
  if (t < 16) {
    float m = -1e30f;
    for (int j = 0; j < 16; j++) m = fmaxf(m, lg[j]);
    float s = 0.f;
    for (int j = 0; j < 16; j++) s += expf(lg[j] - m);
    out[g * 16 + t] = expf(lg[t] - m) / s;
  }
}

extern "C" void kernel_launch(void* const* d_in, const int* in_sizes, int n_in,
                              void* d_out, int out_size, void* d_ws, size_t ws_size,
                              hipStream_t stream) {
  const float* x = (const float*)d_in[0];
  const void* edge = d_in[1];
  const void* batch = d_in[2];
  const float* W[4] = {(const float*)d_in[3], (const float*)d_in[5],
                       (const float*)d_in[7], (const float*)d_in[9]};
  const float* b[4] = {(const float*)d_in[4], (const float*)d_in[6],
                       (const float*)d_in[8], (const float*)d_in[10]};
  const float* Wlin = (const float*)d_in[11];
  const float* blin = (const float*)d_in[12];
  float* out = (float*)d_out;

  int n = in_sizes[0] / 128;
  int E = in_sizes[1] / 2;
  int ngraphs = out_size / 16;

  char* ws = (char*)d_ws;
  size_t off = 0;
  auto alloc = [&](size_t bytes) -> void* {
    void* p = ws + off;
    off = (off + bytes + 255) & ~(size_t)255;
    return p;
  };
  int* flag = (int*)alloc(4);
  int* cnt = (int*)alloc((size_t)n * 4);
  int* offs = (int*)alloc((size_t)(n + 1) * 4);
  int* cursor = (int*)alloc((size_t)n * 4);
  float* dinv = (float*)alloc((size_t)n * 4);
  int* bsum = (int*)alloc(1024 * 4);
  int2* csr_pair = (int2*)alloc((size_t)E * 8);
  // union region: g16 (n*128 fp16, live gemm->agg per layer) and bufA
  // (n*128 fp32, live agg3->pool, after g16 is dead) share storage.
  char* uni = (char*)alloc((size_t)n * 128 * 4);
  uint2* g16 = (uint2*)uni;            // gemm fp16 output (n*32 uint2)
  float* bufA = (float*)uni;           // agg3 fp32 output
  float* bufB = (float*)alloc((size_t)n * 128 * 4);   // agg0/1 fp32 out (gemm A)
  __half2* h16b = (__half2*)alloc((size_t)n * 128 * 2);  // agg2 fp16 out
  float* sums = (float*)alloc((size_t)ngraphs * 128 * 4);
  float* cnts = (float*)alloc((size_t)ngraphs * 4);

  hipMemsetAsync(cnt, 0, (size_t)n * 4, stream);
  hipMemsetAsync(sums, 0, (size_t)ngraphs * 128 * 4, stream);
  hipMemsetAsync(cnts, 0, (size_t)ngraphs * 4, stream);
  k_detect<<<1, 64, 0, stream>>>((const int*)edge, flag);
  k_count<<<(E + 255) / 256, 256, 0, stream>>>(edge, E, cnt, flag);
  k_dinv<<<(n + 255) / 256, 256, 0, stream>>>(cnt, n, dinv);
  int nb = (n + 255) / 256;
  k_scan1<<<nb, 256, 0, stream>>>(cnt, offs, bsum, n);
  k_scan2<<<1, 256, 0, stream>>>(bsum, nb);
  k_scan3<<<nb, 256, 0, stream>>>(offs, cursor, bsum, n, E);
  k_fill<<<(E + 255) / 256, 256, 0, stream>>>(edge, E, dinv, cursor, csr_pair, flag);

  int nrt = (n + RT - 1) / RT;
  int nagg = (n + 3) / 4;
  // layer 0
  k_gemm<<<nrt * 2, 256, 0, stream>>>(x, W[0], g16, n);
  k_agg<<<nagg, 256, 0, stream>>>((const __half2*)g16, offs, csr_pair, dinv,
                                  b[0], bufB, nullptr, n, 1);
  // layer 1
  k_gemm<<<nrt * 2, 256, 0, stream>>>(bufB, W[1], g16, n);
  k_agg<<<nagg, 256, 0, stream>>>((const __half2*)g16, offs, csr_pair, dinv,
                                  b[1], bufB, nullptr, n, 1);
  // layer 2 (agg writes fp16 only; its output is consumed solely by agg3)
  k_gemm<<<nrt * 2, 256, 0, stream>>>(bufB, W[2], g16, n);
  k_agg<<<nagg, 256, 0, stream>>>((const __half2*)g16, offs, csr_pair, dinv,
                                  b[2], nullptr, h16b, n, 1);
  // layer 4 agg: no bias/relu; W3+b3 applied post-pool in k_final.
  // writes bufA (aliases g16 region, which is dead here).
  k_agg<<<nagg, 256, 0, stream>>>(h16b, offs, csr_pair, dinv,
                                  nullptr, bufA, nullptr, n, 0);
  k_pool_partial<<<(n + POOL_CH - 1) / POOL_CH, 128, 0, stream>>>(bufA, batch, n, sums, cnts, flag);
  k_final<<<ngraphs, 128, 0, stream>>>(sums, cnts, W[3], b[3], Wlin, blin, out);
}

// Round 7
// 288.017 us; speedup vs baseline: 2.7149x; 1.2620x over previous
//
#include <hip/hip_runtime.h>
#include <hip/hip_fp16.h>

// ---------------------------------------------------------------------------
// GCN forward: 3x (MFMA fp16 GEMM 50000x128x128 + CSR agg) + layer-4 agg +
// chunked pool (W3 commuted past mean-pool) + fused final chain + softmax.
// Node features fp16, weights repacked fp16, all accumulation fp32.
// ---------------------------------------------------------------------------

typedef _Float16 half8 __attribute__((ext_vector_type(8)));
typedef float f32x4 __attribute__((ext_vector_type(4)));

__device__ __forceinline__ int idx_at(const void* p, long long i, int is64) {
  return is64 ? (int)((const long long*)p)[i] : ((const int*)p)[i];
}

__global__ void k_detect(const int* __restrict__ edge, int* __restrict__ flag) {
  if (threadIdx.x == 0 && blockIdx.x == 0) {
    int all0 = 1;
    for (int i = 1; i < 128; i += 2)
      if (edge[i] != 0) { all0 = 0; break; }
    *flag = all0;
  }
}

__global__ void k_count(const void* __restrict__ edge, int E,
                        int* __restrict__ cnt, const int* __restrict__ flag) {
  int e = blockIdx.x * 256 + threadIdx.x;
  int is64 = *flag;
  if (e < E) {
    int c = idx_at(edge, (long long)E + e, is64);  // col = target
    atomicAdd(&cnt[c], 1);
  }
}

__global__ void k_dinv(const int* __restrict__ cnt, int n, float* __restrict__ dinv) {
  int i = blockIdx.x * 256 + threadIdx.x;
  if (i < n) dinv[i] = rsqrtf((float)(cnt[i] + 1));  // +1 self loop
}

// --- 3-kernel exclusive scan over cnt[n] -> offs[n] -------------------------
__global__ void k_scan1(const int* __restrict__ cnt, int* __restrict__ offs,
                        int* __restrict__ bsum, int n) {
  __shared__ int lds[256];
  int i = blockIdx.x * 256 + threadIdx.x;
  int v = (i < n) ? cnt[i] : 0;
  lds[threadIdx.x] = v;
  __syncthreads();
  for (int off = 1; off < 256; off <<= 1) {
    int t = (threadIdx.x >= off) ? lds[threadIdx.x - off] : 0;
    __syncthreads();
    lds[threadIdx.x] += t;
    __syncthreads();
  }
  if (i < n) offs[i] = lds[threadIdx.x] - v;
  if (threadIdx.x == 255) bsum[blockIdx.x] = lds[255];
}

__global__ void k_scan2(int* __restrict__ bsum, int nb) {
  __shared__ int lds[256];
  int v = (threadIdx.x < nb) ? bsum[threadIdx.x] : 0;
  lds[threadIdx.x] = v;
  __syncthreads();
  for (int off = 1; off < 256; off <<= 1) {
    int t = (threadIdx.x >= off) ? lds[threadIdx.x - off] : 0;
    __syncthreads();
    lds[threadIdx.x] += t;
    __syncthreads();
  }
  if (threadIdx.x < nb) bsum[threadIdx.x] = lds[threadIdx.x] - v;
}

__global__ void k_scan3(int* __restrict__ offs, int* __restrict__ cursor,
                        const int* __restrict__ bsum, int n, int E) {
  int i = blockIdx.x * 256 + threadIdx.x;
  if (i < n) {
    int o = offs[i] + bsum[blockIdx.x];
    offs[i] = o;
    cursor[i] = o;
  }
  if (i == 0) offs[n] = E;
}

// csr_pair[p] = {source_row, bitcast(norm)}
__global__ void k_fill(const void* __restrict__ edge, int E,
                       const float* __restrict__ dinv, int* __restrict__ cursor,
                       int2* __restrict__ csr_pair, const int* __restrict__ flag) {
  int e = blockIdx.x * 256 + threadIdx.x;
  int is64 = *flag;
  if (e < E) {
    int r = idx_at(edge, e, is64);
    int c = idx_at(edge, (long long)E + e, is64);
    int p = atomicAdd(&cursor[c], 1);
    float nm = dinv[r] * dinv[c];
    csr_pair[p] = int2{r, __float_as_int(nm)};
  }
}

// --- W repack: fp32 [k][c] -> fp16 fragment order ---------------------------
// frag idx for (k,c): cb=c>>4, cl=c&15, ks=k>>5, kk=k&31 ->
//   lane=(kk>>3)*16+cl, j=kk&7; out[((cb*4+ks)*64+lane)*8+j]
__global__ void k_wprep(const float* __restrict__ W, _Float16* __restrict__ Wp) {
  int t = blockIdx.x * 256 + threadIdx.x;
  if (t < 16384) {
    int k = t >> 7, c = t & 127;
    int cb = c >> 4, cl = c & 15, ks = k >> 5, kk = k & 31;
    int lane = (kk >> 3) * 16 + cl, j = kk & 7;
    Wp[((cb * 4 + ks) * 64 + lane) * 8 + j] = (_Float16)W[t];
  }
}

// --- MFMA GEMM: C16[n x 128] = A[n x 128] @ W[128 x 128] --------------------
// 4 waves/block, wave = 16 rows x 128 cols x K=128 (32 mfma_f32_16x16x32_f16).
// A from fp16 (or fp32 for layer 0, converted in-register). W frags from LDS.
__global__ __launch_bounds__(256) void k_gemm16(const _Float16* __restrict__ A16,
                                                const float* __restrict__ A32,
                                                const _Float16* __restrict__ Wp,
                                                _Float16* __restrict__ C16, int n) {
  __shared__ float4 Wl[2048];  // 32 KB prepped W
  int t = threadIdx.x;
  const float4* Wp4 = (const float4*)Wp;
#pragma unroll
  for (int i = 0; i < 8; i++) Wl[t + 256 * i] = Wp4[t + 256 * i];
  __syncthreads();
  int wave = t >> 6, l = t & 63;
  int m = blockIdx.x * 64 + wave * 16;
  int lr = l & 15, lg = l >> 4;
  int arow = m + lr;
  if (arow > n - 1) arow = n - 1;  // clamp: D rows are independent; stores guarded
  half8 a[4];
  if (A16) {
#pragma unroll
    for (int ks = 0; ks < 4; ks++)
      a[ks] = *(const half8*)(A16 + (size_t)arow * 128 + ks * 32 + lg * 8);
  } else {
#pragma unroll
    for (int ks = 0; ks < 4; ks++) {
      const float4* s = (const float4*)(A32 + (size_t)arow * 128 + ks * 32 + lg * 8);
      float4 s0 = s[0], s1 = s[1];
      half8 v;
      v[0] = (_Float16)s0.x; v[1] = (_Float16)s0.y;
      v[2] = (_Float16)s0.z; v[3] = (_Float16)s0.w;
      v[4] = (_Float16)s1.x; v[5] = (_Float16)s1.y;
      v[6] = (_Float16)s1.z; v[7] = (_Float16)s1.w;
      a[ks] = v;
    }
  }
  const half8* WlH = (const half8*)Wl;
  f32x4 acc[8];
#pragma unroll
  for (int cb = 0; cb < 8; cb++) {
    f32x4 c = {0.f, 0.f, 0.f, 0.f};
#pragma unroll
    for (int ks = 0; ks < 4; ks++) {
      half8 bfrag = WlH[(cb * 4 + ks) * 64 + l];
      c = __builtin_amdgcn_mfma_f32_16x16x32_f16(a[ks], bfrag, c, 0, 0, 0);
    }
    acc[cb] = c;
  }
  // D: lane l, reg i -> C[m + lg*4 + i][cb*16 + lr]
#pragma unroll
  for (int i = 0; i < 4; i++) {
    int r = m + lg * 4 + i;
    if (r < n) {
#pragma unroll
      for (int cb = 0; cb < 8; cb++)
        C16[(size_t)r * 128 + cb * 16 + lr] = (_Float16)acc[cb][i];
    }
  }
}

// --- Gather core: one wave per node, one half2/lane, 8-deep pipeline --------
__device__ __forceinline__ float2 gather16(const __half2* __restrict__ h16,
                                           const int* __restrict__ offs,
                                           const int2* __restrict__ csr_pair,
                                           const float* __restrict__ dinv,
                                           int node, int lane) {
  int s = offs[node], e = offs[node + 1];
  float dn = dinv[node];
  float2 self = __half22float2(h16[(size_t)node * 64 + lane]);
  float ax = self.x * dn * dn;
  float ay = self.y * dn * dn;
  int i = s;
  if ((i & 1) && i < e) {  // align to int4 pairs
    int2 p = csr_pair[i];
    float2 v = __half22float2(h16[(size_t)p.x * 64 + lane]);
    float f = __int_as_float(p.y);
    ax += v.x * f; ay += v.y * f;
    i++;
  }
  const int4* cp4 = (const int4*)csr_pair;
  for (; i + 8 <= e; i += 8) {
    int4 q0 = cp4[(i >> 1) + 0];
    int4 q1 = cp4[(i >> 1) + 1];
    int4 q2 = cp4[(i >> 1) + 2];
    int4 q3 = cp4[(i >> 1) + 3];
    float2 v0 = __half22float2(h16[(size_t)q0.x * 64 + lane]);
    float2 v1 = __half22float2(h16[(size_t)q0.z * 64 + lane]);
    float2 v2 = __half22float2(h16[(size_t)q1.x * 64 + lane]);
    float2 v3 = __half22float2(h16[(size_t)q1.z * 64 + lane]);
    float2 v4 = __half22float2(h16[(size_t)q2.x * 64 + lane]);
    float2 v5 = __half22float2(h16[(size_t)q2.z * 64 + lane]);
    float2 v6 = __half22float2(h16[(size_t)q3.x * 64 + lane]);
    float2 v7 = __half22float2(h16[(size_t)q3.z * 64 + lane]);
    float f0 = __int_as_float(q0.y), f1 = __int_as_float(q0.w);
    float f2 = __int_as_float(q1.y), f3 = __int_as_float(q1.w);
    float f4 = __int_as_float(q2.y), f5 = __int_as_float(q2.w);
    float f6 = __int_as_float(q3.y), f7 = __int_as_float(q3.w);
    ax += v0.x * f0; ay += v0.y * f0;
    ax += v1.x * f1; ay += v1.y * f1;
    ax += v2.x * f2; ay += v2.y * f2;
    ax += v3.x * f3; ay += v3.y * f3;
    ax += v4.x * f4; ay += v4.y * f4;
    ax += v5.x * f5; ay += v5.y * f5;
    ax += v6.x * f6; ay += v6.y * f6;
    ax += v7.x * f7; ay += v7.y * f7;
  }
  for (; i + 2 <= e; i += 2) {
    int4 q = cp4[i >> 1];
    float2 v0 = __half22float2(h16[(size_t)q.x * 64 + lane]);
    float2 v1 = __half22float2(h16[(size_t)q.z * 64 + lane]);
    float f0 = __int_as_float(q.y), f1 = __int_as_float(q.w);
    ax += v0.x * f0; ay += v0.y * f0;
    ax += v1.x * f1; ay += v1.y * f1;
  }
  if (i < e) {
    int2 p = csr_pair[i];
    float2 v = __half22float2(h16[(size_t)p.x * 64 + lane]);
    float f = __int_as_float(p.y);
    ax += v.x * f; ay += v.y * f;
  }
  return float2{ax, ay};
}

__global__ __launch_bounds__(256) void k_agg(const __half2* __restrict__ h16,
                                             const int* __restrict__ offs,
                                             const int2* __restrict__ csr_pair,
                                             const float* __restrict__ dinv,
                                             const float* __restrict__ bias,
                                             __half2* __restrict__ out16,
                                             int n, int relu) {
  int node = blockIdx.x * 4 + (threadIdx.x >> 6);
  if (node >= n) return;
  int lane = threadIdx.x & 63;
  float2 r = gather16(h16, offs, csr_pair, dinv, node, lane);
  float ax = r.x, ay = r.y;
  if (bias) {
    float2 bb = ((const float2*)bias)[lane];
    ax += bb.x; ay += bb.y;
  }
  if (relu) { ax = fmaxf(ax, 0.f); ay = fmaxf(ay, 0.f); }
  out16[(size_t)node * 64 + lane] = __floats2half2_rn(ax, ay);
}

// --- Mean pool (fp16 input): chunked partial sums + atomics -----------------
#define POOL_CH 64
__global__ __launch_bounds__(128) void k_pool_partial(
    const _Float16* __restrict__ h, const void* __restrict__ batch, int n,
    float* __restrict__ sums, float* __restrict__ cnts,
    const int* __restrict__ flag) {
  int start = blockIdx.x * POOL_CH;
  if (start >= n) return;
  int end = start + POOL_CH;
  if (end > n) end = n;
  int f = threadIdx.x;  // 128 feature lanes
  int is64 = *flag;
  int g = idx_at(batch, start, is64);
  float acc = 0.f, c = 0.f;
  for (int i = start; i < end; i++) {
    int gi = idx_at(batch, i, is64);
    if (gi != g) {
      atomicAdd(&sums[g * 128 + f], acc);
      if (f == 0) atomicAdd(&cnts[g], c);
      acc = 0.f; c = 0.f; g = gi;
    }
    acc += (float)h[(size_t)i * 128 + f];
    c += 1.f;
  }
  atomicAdd(&sums[g * 128 + f], acc);
  if (f == 0) atomicAdd(&cnts[g], c);
}

// pooled = sums/cnt; t1 = pooled@W3+b3; logits = t1@Wlin+blin; softmax.
__global__ __launch_bounds__(128) void k_final(const float* __restrict__ sums,
                                               const float* __restrict__ cnts,
                                               const float* __restrict__ W3,
                                               const float* __restrict__ b3,
                                               const float* __restrict__ Wlin,
                                               const float* __restrict__ blin,
                                               float* __restrict__ out) {
  __shared__ float p[128];
  __shared__ float t1[128];
  __shared__ float lg[16];
  int g = blockIdx.x;
  int t = threadIdx.x;
  float inv = 1.f / fmaxf(cnts[g], 1.f);
  p[t] = sums[g * 128 + t] * inv;
  __syncthreads();
  float acc = 0.f;
  for (int k = 0; k < 128; k++) acc += p[k] * W3[k * 128 + t];
  t1[t] = acc + b3[t];
  __syncthreads();
  if (t < 16) {
    float a2 = 0.f;
    for (int k = 0; k < 128; k++) a2 += t1[k] * Wlin[k * 16 + t];
    lg[t] = a2 + blin[t];
  }
  __syncthreads();
  if (t < 16) {
    float m = -1e30f;
    for (int j = 0; j < 16; j++) m = fmaxf(m, lg[j]);
    float s = 0.f;
    for (int j = 0; j < 16; j++) s += expf(lg[j] - m);
    out[g * 16 + t] = expf(lg[t] - m) / s;
  }
}

extern "C" void kernel_launch(void* const* d_in, const int* in_sizes, int n_in,
                              void* d_out, int out_size, void* d_ws, size_t ws_size,
                              hipStream_t stream) {
  const float* x = (const float*)d_in[0];
  const void* edge = d_in[1];
  const void* batch = d_in[2];
  const float* W[4] = {(const float*)d_in[3], (const float*)d_in[5],
                       (const float*)d_in[7], (const float*)d_in[9]};
  const float* b[4] = {(const float*)d_in[4], (const float*)d_in[6],
                       (const float*)d_in[8], (const float*)d_in[10]};
  const float* Wlin = (const float*)d_in[11];
  const float* blin = (const float*)d_in[12];
  float* out = (float*)d_out;

  int n = in_sizes[0] / 128;
  int E = in_sizes[1] / 2;
  int ngraphs = out_size / 16;

  char* ws = (char*)d_ws;
  size_t off = 0;
  auto alloc = [&](size_t bytes) -> void* {
    void* p = ws + off;
    off = (off + bytes + 255) & ~(size_t)255;
    return p;
  };
  int* flag = (int*)alloc(4);
  int* cnt = (int*)alloc((size_t)n * 4);
  int* offs = (int*)alloc((size_t)(n + 1) * 4);
  int* cursor = (int*)alloc((size_t)n * 4);
  float* dinv = (float*)alloc((size_t)n * 4);
  int* bsum = (int*)alloc(1024 * 4);
  int2* csr_pair = (int2*)alloc((size_t)E * 8);
  _Float16* Wp0 = (_Float16*)alloc(16384 * 2);
  _Float16* Wp1 = (_Float16*)alloc(16384 * 2);
  _Float16* Wp2 = (_Float16*)alloc(16384 * 2);
  _Float16* hA = (_Float16*)alloc((size_t)n * 128 * 2);  // gemm out / agg3 out
  _Float16* hB = (_Float16*)alloc((size_t)n * 128 * 2);  // agg out (gemm A)
  float* sums = (float*)alloc((size_t)ngraphs * 128 * 4);
  float* cnts = (float*)alloc((size_t)ngraphs * 4);

  hipMemsetAsync(cnt, 0, (size_t)n * 4, stream);
  hipMemsetAsync(sums, 0, (size_t)ngraphs * 128 * 4, stream);
  hipMemsetAsync(cnts, 0, (size_t)ngraphs * 4, stream);
  k_detect<<<1, 64, 0, stream>>>((const int*)edge, flag);
  k_count<<<(E + 255) / 256, 256, 0, stream>>>(edge, E, cnt, flag);
  k_dinv<<<(n + 255) / 256, 256, 0, stream>>>(cnt, n, dinv);
  int nb = (n + 255) / 256;
  k_scan1<<<nb, 256, 0, stream>>>(cnt, offs, bsum, n);
  k_scan2<<<1, 256, 0, stream>>>(bsum, nb);
  k_scan3<<<nb, 256, 0, stream>>>(offs, cursor, bsum, n, E);
  k_fill<<<(E + 255) / 256, 256, 0, stream>>>(edge, E, dinv, cursor, csr_pair, flag);
  k_wprep<<<64, 256, 0, stream>>>(W[0], Wp0);
  k_wprep<<<64, 256, 0, stream>>>(W[1], Wp1);
  k_wprep<<<64, 256, 0, stream>>>(W[2], Wp2);

  int ngb = (n + 63) / 64;   // gemm blocks (64 rows each)
  int nagg = (n + 3) / 4;
  // layer 0 (A = x fp32, converted in-register)
  k_gemm16<<<ngb, 256, 0, stream>>>(nullptr, x, Wp0, hA, n);
  k_agg<<<nagg, 256, 0, stream>>>((const __half2*)hA, offs, csr_pair, dinv,
                                  b[0], (__half2*)hB, n, 1);
  // layer 1
  k_gemm16<<<ngb, 256, 0, stream>>>(hB, nullptr, Wp1, hA, n);
  k_agg<<<nagg, 256, 0, stream>>>((const __half2*)hA, offs, csr_pair, dinv,
                                  b[1], (__half2*)hB, n, 1);
  // layer 2
  k_gemm16<<<ngb, 256, 0, stream>>>(hB, nullptr, Wp2, hA, n);
  k_agg<<<nagg, 256, 0, stream>>>((const __half2*)hA, offs, csr_pair, dinv,
                                  b[2], (__half2*)hB, n, 1);
  // layer 4 agg (no bias/relu); W3+b3 applied post-pool in k_final
  k_agg<<<nagg, 256, 0, stream>>>((const __half2*)hB, offs, csr_pair, dinv,
                                  nullptr, (__half2*)hA, n, 0);
  k_pool_partial<<<(n + POOL_CH - 1) / POOL_CH, 128, 0, stream>>>(hA, batch, n, sums, cnts, flag);
  k_final<<<ngraphs, 128, 0, stream>>>(sums, cnts, W[3], b[3], Wlin, blin, out);
}

// Round 8
// 264.517 us; speedup vs baseline: 2.9561x; 1.0888x over previous
//
#include <hip/hip_runtime.h>
#include <hip/hip_fp16.h>

// ---------------------------------------------------------------------------
// GCN forward: 3x (MFMA fp16 GEMM 50000x128x128 + CSR agg) + layer-4 agg +
// chunked pool (W3 commuted past mean-pool) + fused final chain + softmax.
// Node features fp16, weights repacked fp16, all accumulation fp32.
// Agg: 4 nodes/wave, 16 lanes/node, dwordx4 gathers (1KB per instruction).
// ---------------------------------------------------------------------------

typedef _Float16 half8 __attribute__((ext_vector_type(8)));
typedef float f32x4 __attribute__((ext_vector_type(4)));

__device__ __forceinline__ int idx_at(const void* p, long long i, int is64) {
  return is64 ? (int)((const long long*)p)[i] : ((const int*)p)[i];
}

__global__ void k_detect(const int* __restrict__ edge, int* __restrict__ flag) {
  if (threadIdx.x == 0 && blockIdx.x == 0) {
    int all0 = 1;
    for (int i = 1; i < 128; i += 2)
      if (edge[i] != 0) { all0 = 0; break; }
    *flag = all0;
  }
}

__global__ void k_count(const void* __restrict__ edge, int E,
                        int* __restrict__ cnt, const int* __restrict__ flag) {
  int e = blockIdx.x * 256 + threadIdx.x;
  int is64 = *flag;
  if (e < E) {
    int c = idx_at(edge, (long long)E + e, is64);  // col = target
    atomicAdd(&cnt[c], 1);
  }
}

__global__ void k_dinv(const int* __restrict__ cnt, int n, float* __restrict__ dinv) {
  int i = blockIdx.x * 256 + threadIdx.x;
  if (i < n) dinv[i] = rsqrtf((float)(cnt[i] + 1));  // +1 self loop
}

// --- 3-kernel exclusive scan over cnt[n] -> offs[n] -------------------------
__global__ void k_scan1(const int* __restrict__ cnt, int* __restrict__ offs,
                        int* __restrict__ bsum, int n) {
  __shared__ int lds[256];
  int i = blockIdx.x * 256 + threadIdx.x;
  int v = (i < n) ? cnt[i] : 0;
  lds[threadIdx.x] = v;
  __syncthreads();
  for (int off = 1; off < 256; off <<= 1) {
    int t = (threadIdx.x >= off) ? lds[threadIdx.x - off] : 0;
    __syncthreads();
    lds[threadIdx.x] += t;
    __syncthreads();
  }
  if (i < n) offs[i] = lds[threadIdx.x] - v;
  if (threadIdx.x == 255) bsum[blockIdx.x] = lds[255];
}

__global__ void k_scan2(int* __restrict__ bsum, int nb) {
  __shared__ int lds[256];
  int v = (threadIdx.x < nb) ? bsum[threadIdx.x] : 0;
  lds[threadIdx.x] = v;
  __syncthreads();
  for (int off = 1; off < 256; off <<= 1) {
    int t = (threadIdx.x >= off) ? lds[threadIdx.x - off] : 0;
    __syncthreads();
    lds[threadIdx.x] += t;
    __syncthreads();
  }
  if (threadIdx.x < nb) bsum[threadIdx.x] = lds[threadIdx.x] - v;
}

__global__ void k_scan3(int* __restrict__ offs, int* __restrict__ cursor,
                        const int* __restrict__ bsum, int n, int E) {
  int i = blockIdx.x * 256 + threadIdx.x;
  if (i < n) {
    int o = offs[i] + bsum[blockIdx.x];
    offs[i] = o;
    cursor[i] = o;
  }
  if (i == 0) offs[n] = E;
}

// csr_pair[p] = {source_row, bitcast(norm)}
__global__ void k_fill(const void* __restrict__ edge, int E,
                       const float* __restrict__ dinv, int* __restrict__ cursor,
                       int2* __restrict__ csr_pair, const int* __restrict__ flag) {
  int e = blockIdx.x * 256 + threadIdx.x;
  int is64 = *flag;
  if (e < E) {
    int r = idx_at(edge, e, is64);
    int c = idx_at(edge, (long long)E + e, is64);
    int p = atomicAdd(&cursor[c], 1);
    float nm = dinv[r] * dinv[c];
    csr_pair[p] = int2{r, __float_as_int(nm)};
  }
}

// --- W repack: fp32 [k][c] -> fp16 fragment order ---------------------------
__global__ void k_wprep(const float* __restrict__ W, _Float16* __restrict__ Wp) {
  int t = blockIdx.x * 256 + threadIdx.x;
  if (t < 16384) {
    int k = t >> 7, c = t & 127;
    int cb = c >> 4, cl = c & 15, ks = k >> 5, kk = k & 31;
    int lane = (kk >> 3) * 16 + cl, j = kk & 7;
    Wp[((cb * 4 + ks) * 64 + lane) * 8 + j] = (_Float16)W[t];
  }
}

// --- MFMA GEMM: C16[n x 128] = A[n x 128] @ W[128 x 128] --------------------
__global__ __launch_bounds__(256) void k_gemm16(const _Float16* __restrict__ A16,
                                                const float* __restrict__ A32,
                                                const _Float16* __restrict__ Wp,
                                                _Float16* __restrict__ C16, int n) {
  __shared__ float4 Wl[2048];  // 32 KB prepped W
  int t = threadIdx.x;
  const float4* Wp4 = (const float4*)Wp;
#pragma unroll
  for (int i = 0; i < 8; i++) Wl[t + 256 * i] = Wp4[t + 256 * i];
  __syncthreads();
  int wave = t >> 6, l = t & 63;
  int m = blockIdx.x * 64 + wave * 16;
  int lr = l & 15, lg = l >> 4;
  int arow = m + lr;
  if (arow > n - 1) arow = n - 1;  // clamp: stores guarded below
  half8 a[4];
  if (A16) {
#pragma unroll
    for (int ks = 0; ks < 4; ks++)
      a[ks] = *(const half8*)(A16 + (size_t)arow * 128 + ks * 32 + lg * 8);
  } else {
#pragma unroll
    for (int ks = 0; ks < 4; ks++) {
      const float4* s = (const float4*)(A32 + (size_t)arow * 128 + ks * 32 + lg * 8);
      float4 s0 = s[0], s1 = s[1];
      half8 v;
      v[0] = (_Float16)s0.x; v[1] = (_Float16)s0.y;
      v[2] = (_Float16)s0.z; v[3] = (_Float16)s0.w;
      v[4] = (_Float16)s1.x; v[5] = (_Float16)s1.y;
      v[6] = (_Float16)s1.z; v[7] = (_Float16)s1.w;
      a[ks] = v;
    }
  }
  const half8* WlH = (const half8*)Wl;
  f32x4 acc[8];
#pragma unroll
  for (int cb = 0; cb < 8; cb++) {
    f32x4 c = {0.f, 0.f, 0.f, 0.f};
#pragma unroll
    for (int ks = 0; ks < 4; ks++) {
      half8 bfrag = WlH[(cb * 4 + ks) * 64 + l];
      c = __builtin_amdgcn_mfma_f32_16x16x32_f16(a[ks], bfrag, c, 0, 0, 0);
    }
    acc[cb] = c;
  }
#pragma unroll
  for (int i = 0; i < 4; i++) {
    int r = m + lg * 4 + i;
    if (r < n) {
#pragma unroll
      for (int cb = 0; cb < 8; cb++)
        C16[(size_t)r * 128 + cb * 16 + lr] = (_Float16)acc[cb][i];
    }
  }
}

// --- Agg: 4 nodes/wave, 16 lanes/node, 16B/lane gathers ---------------------
__device__ __forceinline__ void fma8(float* acc, uint4 r, float w) {
  union { uint4 u; __half2 h[4]; } cv;
  cv.u = r;
#pragma unroll
  for (int q = 0; q < 4; q++) {
    float2 v = __half22float2(cv.h[q]);
    acc[2 * q] += v.x * w;
    acc[2 * q + 1] += v.y * w;
  }
}

__global__ __launch_bounds__(256) void k_agg(const uint4* __restrict__ h16,
                                             const int* __restrict__ offs,
                                             const int2* __restrict__ csr_pair,
                                             const float* __restrict__ dinv,
                                             const float* __restrict__ bias,
                                             uint4* __restrict__ out16,
                                             int n, int relu) {
  int t = threadIdx.x;
  int wave = t >> 6, l = t & 63;
  int g = l >> 4, sl = l & 15;
  int node = blockIdx.x * 16 + wave * 4 + g;
  if (node >= n) return;
  int s = offs[node], e = offs[node + 1];
  float dn = dinv[node];
  float acc[8];
  // self term
  {
    uint4 r = h16[(size_t)node * 16 + sl];
    union { uint4 u; __half2 h[4]; } cv;
    cv.u = r;
    float w = dn * dn;
#pragma unroll
    for (int q = 0; q < 4; q++) {
      float2 v = __half22float2(cv.h[q]);
      acc[2 * q] = v.x * w;
      acc[2 * q + 1] = v.y * w;
    }
  }
  int i = s;
  for (; i + 4 <= e; i += 4) {
    int2 p0 = csr_pair[i];
    int2 p1 = csr_pair[i + 1];
    int2 p2 = csr_pair[i + 2];
    int2 p3 = csr_pair[i + 3];
    uint4 r0 = h16[(size_t)p0.x * 16 + sl];
    uint4 r1 = h16[(size_t)p1.x * 16 + sl];
    uint4 r2 = h16[(size_t)p2.x * 16 + sl];
    uint4 r3 = h16[(size_t)p3.x * 16 + sl];
    fma8(acc, r0, __int_as_float(p0.y));
    fma8(acc, r1, __int_as_float(p1.y));
    fma8(acc, r2, __int_as_float(p2.y));
    fma8(acc, r3, __int_as_float(p3.y));
  }
  for (; i < e; i++) {
    int2 p = csr_pair[i];
    uint4 r = h16[(size_t)p.x * 16 + sl];
    fma8(acc, r, __int_as_float(p.y));
  }
  if (bias) {
    const float4* b4 = (const float4*)(bias + sl * 8);
    float4 b0 = b4[0], b1 = b4[1];
    acc[0] += b0.x; acc[1] += b0.y; acc[2] += b0.z; acc[3] += b0.w;
    acc[4] += b1.x; acc[5] += b1.y; acc[6] += b1.z; acc[7] += b1.w;
  }
  if (relu) {
#pragma unroll
    for (int q = 0; q < 8; q++) acc[q] = fmaxf(acc[q], 0.f);
  }
  union { uint4 u; __half2 h[4]; } ov;
#pragma unroll
  for (int q = 0; q < 4; q++)
    ov.h[q] = __floats2half2_rn(acc[2 * q], acc[2 * q + 1]);
  out16[(size_t)node * 16 + sl] = ov.u;
}

// --- Mean pool (fp16 input): chunked partial sums + atomics -----------------
#define POOL_CH 64
__global__ __launch_bounds__(128) void k_pool_partial(
    const _Float16* __restrict__ h, const void* __restrict__ batch, int n,
    float* __restrict__ sums, float* __restrict__ cnts,
    const int* __restrict__ flag) {
  int start = blockIdx.x * POOL_CH;
  if (start >= n) return;
  int end = start + POOL_CH;
  if (end > n) end = n;
  int f = threadIdx.x;  // 128 feature lanes
  int is64 = *flag;
  int g = idx_at(batch, start, is64);
  float acc = 0.f, c = 0.f;
  for (int i = start; i < end; i++) {
    int gi = idx_at(batch, i, is64);
    if (gi != g) {
      atomicAdd(&sums[g * 128 + f], acc);
      if (f == 0) atomicAdd(&cnts[g], c);
      acc = 0.f; c = 0.f; g = gi;
    }
    acc += (float)h[(size_t)i * 128 + f];
    c += 1.f;
  }
  atomicAdd(&sums[g * 128 + f], acc);
  if (f == 0) atomicAdd(&cnts[g], c);
}

// pooled = sums/cnt; t1 = pooled@W3+b3; logits = t1@Wlin+blin; softmax.
__global__ __launch_bounds__(128) void k_final(const float* __restrict__ sums,
                                               const float* __restrict__ cnts,
                                               const float* __restrict__ W3,
                                               const float* __restrict__ b3,
                                               const float* __restrict__ Wlin,
                                               const float* __restrict__ blin,
                                               float* __restrict__ out) {
  __shared__ float p[128];
  __shared__ float t1[128];
  __shared__ float lg[16];
  int g = blockIdx.x;
  int t = threadIdx.x;
  float inv = 1.f / fmaxf(cnts[g], 1.f);
  p[t] = sums[g * 128 + t] * inv;
  __syncthreads();
  float acc = 0.f;
  for (int k = 0; k < 128; k++) acc += p[k] * W3[k * 128 + t];
  t1[t] = acc + b3[t];
  __syncthreads();
  if (t < 16) {
    float a2 = 0.f;
    for (int k = 0; k < 128; k++) a2 += t1[k] * Wlin[k * 16 + t];
    lg[t] = a2 + blin[t];
  }
  __syncthreads();
  if (t < 16) {
    float m = -1e30f;
    for (int j = 0; j < 16; j++) m = fmaxf(m, lg[j]);
    float s = 0.f;
    for (int j = 0; j < 16; j++) s += expf(lg[j] - m);
    out[g * 16 + t] = expf(lg[t] - m) / s;
  }
}

extern "C" void kernel_launch(void* const* d_in, const int* in_sizes, int n_in,
                              void* d_out, int out_size, void* d_ws, size_t ws_size,
                              hipStream_t stream) {
  const float* x = (const float*)d_in[0];
  const void* edge = d_in[1];
  const void* batch = d_in[2];
  const float* W[4] = {(const float*)d_in[3], (const float*)d_in[5],
                       (const float*)d_in[7], (const float*)d_in[9]};
  const float* b[4] = {(const float*)d_in[4], (const float*)d_in[6],
                       (const float*)d_in[8], (const float*)d_in[10]};
  const float* Wlin = (const float*)d_in[11];
  const float* blin = (const float*)d_in[12];
  float* out = (float*)d_out;

  int n = in_sizes[0] / 128;
  int E = in_sizes[1] / 2;
  int ngraphs = out_size / 16;

  char* ws = (char*)d_ws;
  size_t off = 0;
  auto alloc = [&](size_t bytes) -> void* {
    void* p = ws + off;
    off = (off + bytes + 255) & ~(size_t)255;
    return p;
  };
  int* flag = (int*)alloc(4);
  int* cnt = (int*)alloc((size_t)n * 4);
  int* offs = (int*)alloc((size_t)(n + 1) * 4);
  int* cursor = (int*)alloc((size_t)n * 4);
  float* dinv = (float*)alloc((size_t)n * 4);
  int* bsum = (int*)alloc(1024 * 4);
  int2* csr_pair = (int2*)alloc((size_t)E * 8);
  _Float16* Wp0 = (_Float16*)alloc(16384 * 2);
  _Float16* Wp1 = (_Float16*)alloc(16384 * 2);
  _Float16* Wp2 = (_Float16*)alloc(16384 * 2);
  _Float16* hA = (_Float16*)alloc((size_t)n * 128 * 2);  // gemm out / agg3 out
  _Float16* hB = (_Float16*)alloc((size_t)n * 128 * 2);  // agg out (gemm A)
  float* sums = (float*)alloc((size_t)ngraphs * 128 * 4);
  float* cnts = (float*)alloc((size_t)ngraphs * 4);

  hipMemsetAsync(cnt, 0, (size_t)n * 4, stream);
  hipMemsetAsync(sums, 0, (size_t)ngraphs * 128 * 4, stream);
  hipMemsetAsync(cnts, 0, (size_t)ngraphs * 4, stream);
  k_detect<<<1, 64, 0, stream>>>((const int*)edge, flag);
  k_count<<<(E + 255) / 256, 256, 0, stream>>>(edge, E, cnt, flag);
  k_dinv<<<(n + 255) / 256, 256, 0, stream>>>(cnt, n, dinv);
  int nb = (n + 255) / 256;
  k_scan1<<<nb, 256, 0, stream>>>(cnt, offs, bsum, n);
  k_scan2<<<1, 256, 0, stream>>>(bsum, nb);
  k_scan3<<<nb, 256, 0, stream>>>(offs, cursor, bsum, n, E);
  k_fill<<<(E + 255) / 256, 256, 0, stream>>>(edge, E, dinv, cursor, csr_pair, flag);
  k_wprep<<<64, 256, 0, stream>>>(W[0], Wp0);
  k_wprep<<<64, 256, 0, stream>>>(W[1], Wp1);
  k_wprep<<<64, 256, 0, stream>>>(W[2], Wp2);

  int ngb = (n + 63) / 64;     // gemm blocks (64 rows each)
  int nagg = (n + 15) / 16;    // agg blocks (16 nodes each)
  // layer 0 (A = x fp32, converted in-register)
  k_gemm16<<<ngb, 256, 0, stream>>>(nullptr, x, Wp0, hA, n);
  k_agg<<<nagg, 256, 0, stream>>>((const uint4*)hA, offs, csr_pair, dinv,
                                  b[0], (uint4*)hB, n, 1);
  // layer 1
  k_gemm16<<<ngb, 256, 0, stream>>>(hB, nullptr, Wp1, hA, n);
  k_agg<<<nagg, 256, 0, stream>>>((const uint4*)hA, offs, csr_pair, dinv,
                                  b[1], (uint4*)hB, n, 1);
  // layer 2
  k_gemm16<<<ngb, 256, 0, stream>>>(hB, nullptr, Wp2, hA, n);
  k_agg<<<nagg, 256, 0, stream>>>((const uint4*)hA, offs, csr_pair, dinv,
                                  b[2], (uint4*)hB, n, 1);
  // layer 4 agg (no bias/relu); W3+b3 applied post-pool in k_final
  k_agg<<<nagg, 256, 0, stream>>>((const uint4*)hB, offs, csr_pair, dinv,
                                  nullptr, (uint4*)hA, n, 0);
  k_pool_partial<<<(n + POOL_CH - 1) / POOL_CH, 128, 0, stream>>>(hA, batch, n, sums, cnts, flag);
  k_final<<<ngraphs, 128, 0, stream>>>(sums, cnts, W[3], b[3], Wlin, blin, out);
}